// Round 5
// baseline (93.247 us; speedup 1.0000x reference)
//
#include <hip/hip_runtime.h>
#include <hip/hip_bf16.h>
#include <math.h>

#define NN 8192
#define CC 256
#define OO 64
#define RCH 512    // rank-count chunk size
#define NCHR 16    // NN/RCH
#define SCH 128    // scan chunks
#define SROWS 64   // rows per scan chunk

// Kernel 1: GEMM (W1 transposed into LDS per block) + fused f1/f2 reductions + exp tables + keys
// block: 256 threads = 16 rows x 64 cols, each thread 2 rows x 2 cols. grid 512.
__global__ __launch_bounds__(256) void k_seq2(
    const float* __restrict__ x, const float* __restrict__ W1,
    const float* __restrict__ b1, const float* __restrict__ a1,
    const float* __restrict__ ba1, const float* __restrict__ a2,
    const float* __restrict__ ba2,
    float* __restrict__ seq,
    float* __restrict__ f1, float* __restrict__ f2,
    float* __restrict__ E1, float* __restrict__ E1s,
    float* __restrict__ eF2, float* __restrict__ eF2s,
    unsigned long long* __restrict__ keys /* [2][NN] */)
{
  __shared__ float w_lds[64][66];   // [c-within-tile][o], pad 66 keeps float2 8B-aligned
  const int t = threadIdx.x;
  const int p = t & 31;             // col pair: o = 2p, 2p+1
  const int g = t >> 5;             // 0..7 row group
  const int r0 = blockIdx.x*16 + g*2;
  const int r1 = r0 + 1;
  float c00 = 0.f, c01 = 0.f, c10 = 0.f, c11 = 0.f;
  for (int ct = 0; ct < 4; ++ct) {
    __syncthreads();
    for (int idx = t; idx < 4096; idx += 256) {
      const int o = idx >> 6, cc = idx & 63;
      w_lds[cc][o] = W1[o*CC + ct*64 + cc];
    }
    __syncthreads();
    const float* xr0 = x + (size_t)r0*CC + ct*64;
    const float* xr1 = x + (size_t)r1*CC + ct*64;
#pragma unroll 4
    for (int c = 0; c < 64; c += 4) {
      const float4 xa = *(const float4*)(xr0 + c);
      const float4 xb = *(const float4*)(xr1 + c);
      const float2 w0 = *(const float2*)&w_lds[c+0][2*p];
      const float2 w1 = *(const float2*)&w_lds[c+1][2*p];
      const float2 w2 = *(const float2*)&w_lds[c+2][2*p];
      const float2 w3 = *(const float2*)&w_lds[c+3][2*p];
      c00 = fmaf(xa.x, w0.x, c00); c00 = fmaf(xa.y, w1.x, c00);
      c00 = fmaf(xa.z, w2.x, c00); c00 = fmaf(xa.w, w3.x, c00);
      c01 = fmaf(xa.x, w0.y, c01); c01 = fmaf(xa.y, w1.y, c01);
      c01 = fmaf(xa.z, w2.y, c01); c01 = fmaf(xa.w, w3.y, c01);
      c10 = fmaf(xb.x, w0.x, c10); c10 = fmaf(xb.y, w1.x, c10);
      c10 = fmaf(xb.z, w2.x, c10); c10 = fmaf(xb.w, w3.x, c10);
      c11 = fmaf(xb.x, w0.y, c11); c11 = fmaf(xb.y, w1.y, c11);
      c11 = fmaf(xb.z, w2.y, c11); c11 = fmaf(xb.w, w3.y, c11);
    }
  }
  const float2 B2 = *(const float2*)&b1[2*p];
  const float v00 = c00 + B2.x, v01 = c01 + B2.y;
  const float v10 = c10 + B2.x, v11 = c11 + B2.y;
  *(float2*)&seq[(size_t)r0*OO + 2*p] = make_float2(v00, v01);
  *(float2*)&seq[(size_t)r1*OO + 2*p] = make_float2(v10, v11);
  const float2 A1 = *(const float2*)&a1[2*p];
  const float2 A2 = *(const float2*)&a2[2*p];
  float p1_0 = v00*A1.x + v01*A1.y;
  float p2_0 = v00*A2.x + v01*A2.y;
  float p1_1 = v10*A1.x + v11*A1.y;
  float p2_1 = v10*A2.x + v11*A2.y;
#pragma unroll
  for (int d = 1; d < 32; d <<= 1) {   // reduce within 32-lane half (one row pair per half)
    p1_0 += __shfl_xor(p1_0, d, 64);
    p2_0 += __shfl_xor(p2_0, d, 64);
    p1_1 += __shfl_xor(p1_1, d, 64);
    p2_1 += __shfl_xor(p2_1, d, 64);
  }
  if (p == 0) {
    const float bba1 = ba1[0], bba2 = ba2[0];
    const float t1a = p1_0 + bba1, t2a = p2_0 + bba2;
    const float t1b = p1_1 + bba1, t2b = p2_1 + bba2;
    f1[r0] = t1a; E1[r0] = expf(t1a); E1s[r0] = expf(0.01f*t1a);
    f2[r0] = t2a; eF2[r0] = expf(t2a); eF2s[r0] = expf(0.01f*t2a);
    f1[r1] = t1b; E1[r1] = expf(t1b); E1s[r1] = expf(0.01f*t1b);
    f2[r1] = t2b; eF2[r1] = expf(t2b); eF2s[r1] = expf(0.01f*t2b);
    unsigned u;
    u = __float_as_uint(t1a); u = (u & 0x80000000u) ? ~u : (u | 0x80000000u);
    keys[r0] = ((unsigned long long)u << 32) | (unsigned)r0;
    u = __float_as_uint(t1b); u = (u & 0x80000000u) ? ~u : (u | 0x80000000u);
    keys[r1] = ((unsigned long long)u << 32) | (unsigned)r1;
    u = __float_as_uint(t2a); u = (u & 0x80000000u) ? ~u : (u | 0x80000000u);
    keys[NN + r0] = ((unsigned long long)u << 32) | (unsigned)r0;
    u = __float_as_uint(t2b); u = (u & 0x80000000u) ? ~u : (u | 0x80000000u);
    keys[NN + r1] = ((unsigned long long)u << 32) | (unsigned)r1;
  }
}

// Kernel 2: brute-force rank counting on u64 keys, per-chunk partial counts (no atomics)
__global__ __launch_bounds__(256) void k_rank(
    const unsigned long long* __restrict__ keys, int* __restrict__ pRank)
{
  const int arr = blockIdx.z;
  const int ch  = blockIdx.y;
  const int j = blockIdx.x*256 + threadIdx.x;
  __shared__ unsigned long long sk[RCH];
  const unsigned long long* kb = keys + (size_t)arr*NN;
  for (int q = threadIdx.x; q < RCH; q += 256)
    sk[q] = kb[ch*RCH + q];
  __syncthreads();
  const unsigned long long my = kb[j];
  int cnt = 0;
#pragma unroll 8
  for (int ii = 0; ii < RCH; ++ii)
    cnt += (sk[ii] < my) ? 1 : 0;
  pRank[(arr*NCHR + ch)*NN + j] = cnt;
}

// Kernel 3: sum rank partials; scatter f1-side tables f1-sorted; f2 f2-sorted; rank2 + inv
__global__ __launch_bounds__(256) void k_scat1(
    const int* __restrict__ pRank, const float* __restrict__ f1,
    const float* __restrict__ E1, const float* __restrict__ E1s,
    const float* __restrict__ f2,
    float* __restrict__ s1, float* __restrict__ se1,
    float* __restrict__ se1s, float* __restrict__ f2s,
    int* __restrict__ rank2, int* __restrict__ inv)
{
  const int i = blockIdx.x*256 + threadIdx.x;
  int r1 = 0, r2 = 0;
#pragma unroll
  for (int ch = 0; ch < NCHR; ++ch) {
    r1 += pRank[ch*NN + i];
    r2 += pRank[(NCHR + ch)*NN + i];
  }
  s1[r1] = f1[i]; se1[r1] = E1[i]; se1s[r1] = E1s[i];
  f2s[r2] = f2[i];
  rank2[i] = r2;
  inv[r2] = i;
}

// Kernel 4: single block 1024 threads: dual exclusive scan of se1/se1s (shfl) -> PreE1/PreE1s,
// then per-j binary search in LDS s1 -> D_j -> Bs/Es written in f2-sorted order.
__global__ __launch_bounds__(1024) void k_mega(
    const float* __restrict__ se1, const float* __restrict__ se1s,
    const float* __restrict__ s1g, const float* __restrict__ f2,
    const float* __restrict__ eF2, const float* __restrict__ eF2s,
    const int* __restrict__ rank2,
    float* __restrict__ PreE1, float* __restrict__ PreE1s,
    float* __restrict__ Bs, float* __restrict__ Es)
{
  __shared__ float s1l[NN];      // 32 KB
  __shared__ float wparts[32];   // 16 wave partials x 2 arrays
  const int t = threadIdx.x;
  const int lane = t & 63, wv = t >> 6;
  const float4 ea = ((const float4*)se1)[t*2];
  const float4 eb = ((const float4*)se1)[t*2+1];
  const float4 fa = ((const float4*)se1s)[t*2];
  const float4 fb = ((const float4*)se1s)[t*2+1];
  const float sA = ((ea.x+ea.y)+(ea.z+ea.w)) + ((eb.x+eb.y)+(eb.z+eb.w));
  const float sB = ((fa.x+fa.y)+(fa.z+fa.w)) + ((fb.x+fb.y)+(fb.z+fb.w));
  float iA = sA, iB = sB;
#pragma unroll
  for (int d = 1; d < 64; d <<= 1) {
    const float uA = __shfl_up(iA, d, 64);
    const float uB = __shfl_up(iB, d, 64);
    if (lane >= d) { iA += uA; iB += uB; }
  }
  if (lane == 63) { wparts[wv] = iA; wparts[16+wv] = iB; }
  __syncthreads();
  float baseA = 0.f, baseB = 0.f, T1 = 0.f;
  for (int q = 0; q < 16; ++q) {
    const float wa = wparts[q];
    T1 += wa;
    if (q < wv) { baseA += wa; baseB += wparts[16+q]; }
  }
  // exclusive running writes for this thread's 8 elements
  float run = baseA + iA - sA;
  float4 ov;
  ov.x = run; run += ea.x; ov.y = run; run += ea.y;
  ov.z = run; run += ea.z; ov.w = run; run += ea.w;
  ((float4*)PreE1)[t*2] = ov;
  ov.x = run; run += eb.x; ov.y = run; run += eb.y;
  ov.z = run; run += eb.z; ov.w = run; run += eb.w;
  ((float4*)PreE1)[t*2+1] = ov;
  if (t == 1023) PreE1[NN] = run;
  run = baseB + iB - sB;
  ov.x = run; run += fa.x; ov.y = run; run += fa.y;
  ov.z = run; run += fa.z; ov.w = run; run += fa.w;
  ((float4*)PreE1s)[t*2] = ov;
  ov.x = run; run += fb.x; ov.y = run; run += fb.y;
  ov.z = run; run += fb.z; ov.w = run; run += fb.w;
  ((float4*)PreE1s)[t*2+1] = ov;
  if (t == 1023) PreE1s[NN] = run;
  // stage s1 into LDS
  for (int q = t; q < NN/4; q += 1024)
    ((float4*)s1l)[q] = ((const float4*)s1g)[q];
  __threadfence();
  __syncthreads();
#pragma unroll
  for (int q = 0; q < 8; ++q) {
    const int j = q*1024 + t;
    const float tgt = -f2[j];
    int lo = 0, hi = NN;
    while (lo < hi) { const int mid = (lo+hi) >> 1; if (s1l[mid] < tgt) lo = mid+1; else hi = mid; }
    const float A  = T1 - PreE1[lo];
    const float Bv = PreE1s[lo];
    const float e2 = eF2[j], e2s = eF2s[j];
    const float D = fmaf(A, e2, Bv*e2s);
    const int r2 = rank2[j];
    Bs[r2] = e2/D;
    Es[r2] = e2s/D;
  }
}

// Kernel 5: per-chunk column totals, gathering seq rows via inv and scaling on the fly
__global__ __launch_bounds__(256) void k_sumchunk(
    const float* __restrict__ seq, const int* __restrict__ inv,
    const float* __restrict__ Bs, const float* __restrict__ Es,
    float* __restrict__ TU, float* __restrict__ TV)
{
  const int b = blockIdx.x, tid = threadIdx.x;
  const int ks = tid >> 6, o = tid & 63;
  float su = 0.f, sv = 0.f;
#pragma unroll 4
  for (int m = 0; m < SROWS/4; ++m) {
    const int kk = b*SROWS + ks*(SROWS/4) + m;
    const int j = inv[kk];
    const float s = seq[(size_t)j*OO + o];
    su = fmaf(Bs[kk], s, su);
    sv = fmaf(Es[kk], s, sv);
  }
  __shared__ float lu[4][64], lv[4][64];
  lu[ks][o] = su; lv[ks][o] = sv;
  __syncthreads();
  if (ks == 0) {
    TU[b*64+o] = lu[0][o]+lu[1][o]+lu[2][o]+lu[3][o];
    TV[b*64+o] = lv[0][o]+lv[1][o]+lv[2][o]+lv[3][o];
  }
}

// Kernel 6: parallel exclusive scan of chunk totals (4 segments of 32); grand totals -> PU/PV[NN]
__global__ __launch_bounds__(256) void k_scanT(
    const float* __restrict__ TU, const float* __restrict__ TV,
    float* __restrict__ baseU, float* __restrict__ baseV,
    float* __restrict__ PU, float* __restrict__ PV)
{
  const int seg = threadIdx.x >> 6, o = threadIdx.x & 63;
  float pu = 0.f, pv = 0.f;
  for (int c = seg*32; c < seg*32+32; ++c) { pu += TU[c*64+o]; pv += TV[c*64+o]; }
  __shared__ float lu[4][64], lv[4][64];
  lu[seg][o] = pu; lv[seg][o] = pv;
  __syncthreads();
  float bu = 0.f, bv = 0.f;
  for (int q = 0; q < seg; ++q) { bu += lu[q][o]; bv += lv[q][o]; }
  float ru = bu, rv = bv;
  for (int c = seg*32; c < seg*32+32; ++c) {
    baseU[c*64+o] = ru; ru += TU[c*64+o];
    baseV[c*64+o] = rv; rv += TV[c*64+o];
  }
  if (seg == 3) { PU[(size_t)NN*OO + o] = ru; PV[(size_t)NN*OO + o] = rv; }
}

// Kernel 7: within-chunk serial exclusive scan (gather + scale) -> PU/PV [NN+1][OO]
// 128 threads: lower wave = U, upper wave = V
__global__ __launch_bounds__(128) void k_scanApply(
    const float* __restrict__ seq, const int* __restrict__ inv,
    const float* __restrict__ Bs, const float* __restrict__ Es,
    const float* __restrict__ baseU, const float* __restrict__ baseV,
    float* __restrict__ PU, float* __restrict__ PV)
{
  const int b = blockIdx.x;
  const int h = threadIdx.x >> 6, o = threadIdx.x & 63;
  const float* __restrict__ S   = h ? Es : Bs;
  const float* __restrict__ bas = h ? baseV : baseU;
  float* __restrict__ dst       = h ? PV : PU;
  float run = bas[b*64 + o];
#pragma unroll 4
  for (int k = 0; k < SROWS; ++k) {
    const int kk = b*SROWS + k;
    const int j = inv[kk];
    dst[(size_t)kk*OO + o] = run;
    run = fmaf(S[kk], seq[(size_t)j*OO + o], run);
  }
}

// Kernel 8: per (i,o): binary search k_i = #{f2 < -f1[i]} (wave-uniform), combine, ELU
__global__ __launch_bounds__(256) void k_final(
    const float* __restrict__ f1, const float* __restrict__ E1,
    const float* __restrict__ E1s, const float* __restrict__ f2s,
    const float* __restrict__ PU, const float* __restrict__ PV,
    float* __restrict__ out)
{
  const int tid = threadIdx.x;
  const int i = blockIdx.x*4 + (tid >> 6);
  const int o = tid & 63;
  const float t = -f1[i];
  int lo = 0, hi = NN;
  while (lo < hi) { const int mid = (lo+hi) >> 1; if (f2s[mid] < t) lo = mid+1; else hi = mid; }
  const size_t k = (size_t)lo;
  const float utot = PU[(size_t)NN*OO + o];
  const float ret = E1[i]*(utot - PU[k*OO+o]) + E1s[i]*PV[k*OO+o];
  out[(size_t)i*OO + o] = ret > 0.f ? ret : expm1f(ret);
}

extern "C" void kernel_launch(void* const* d_in, const int* in_sizes, int n_in,
                              void* d_out, int out_size, void* d_ws, size_t ws_size,
                              hipStream_t stream)
{
  (void)in_sizes; (void)n_in; (void)out_size; (void)ws_size;
  const float* x   = (const float*)d_in[0];
  const float* W1  = (const float*)d_in[1];
  const float* b1  = (const float*)d_in[2];
  const float* a1  = (const float*)d_in[3];
  const float* ba1 = (const float*)d_in[4];
  const float* a2  = (const float*)d_in[5];
  const float* ba2 = (const float*)d_in[6];
  float* out = (float*)d_out;

  float* w = (float*)d_ws;
  size_t off = 0;
  auto alloc = [&](size_t n) { float* p = w + off; off += (n + 63) & ~(size_t)63; return p; };
  float* seq  = alloc((size_t)NN*OO);
  float* f1   = alloc(NN);
  float* f2   = alloc(NN);
  float* E1   = alloc(NN);
  float* E1s  = alloc(NN);
  float* eF2  = alloc(NN);
  float* eF2s = alloc(NN);
  unsigned long long* keys = (unsigned long long*)alloc((size_t)4*NN);
  int*   pRank = (int*)alloc((size_t)2*NCHR*NN);
  int*   rank2 = (int*)alloc(NN);
  int*   inv   = (int*)alloc(NN);
  float* s1   = alloc(NN);
  float* se1  = alloc(NN);
  float* se1s = alloc(NN);
  float* f2s  = alloc(NN);
  float* PreE1  = alloc(NN+64);
  float* PreE1s = alloc(NN+64);
  float* Bs   = alloc(NN);
  float* Es   = alloc(NN);
  float* TU   = alloc(SCH*64);
  float* TV   = alloc(SCH*64);
  float* baseU= alloc(SCH*64);
  float* baseV= alloc(SCH*64);
  float* PU   = alloc((size_t)(NN+1)*OO);
  float* PV   = alloc((size_t)(NN+1)*OO);

  k_seq2<<<512, 256, 0, stream>>>(x, W1, b1, a1, ba1, a2, ba2,
                                  seq, f1, f2, E1, E1s, eF2, eF2s, keys);
  k_rank<<<dim3(32, NCHR, 2), 256, 0, stream>>>(keys, pRank);
  k_scat1<<<32, 256, 0, stream>>>(pRank, f1, E1, E1s, f2, s1, se1, se1s, f2s, rank2, inv);
  k_mega<<<1, 1024, 0, stream>>>(se1, se1s, s1, f2, eF2, eF2s, rank2,
                                 PreE1, PreE1s, Bs, Es);
  k_sumchunk<<<SCH, 256, 0, stream>>>(seq, inv, Bs, Es, TU, TV);
  k_scanT<<<1, 256, 0, stream>>>(TU, TV, baseU, baseV, PU, PV);
  k_scanApply<<<SCH, 128, 0, stream>>>(seq, inv, Bs, Es, baseU, baseV, PU, PV);
  k_final<<<2048, 256, 0, stream>>>(f1, E1, E1s, f2s, PU, PV, out);
}